// Round 15
// baseline (203.031 us; speedup 1.0000x reference)
//
#include <hip/hip_runtime.h>

// GHM-C loss, single pass + tiny reduce.
// loss = sum_b S_b / (count_b * n_nonempty) over nonempty bins b.
//
// R1: same-address atomics FAIL.  R3: LDS RMW hist 123us.  R5: select tree 76us.
// R6: ticket fusion FAIL.  R10: native-trans bitwise-identical (already native).
// R11: stripped 14-instr kernel 58us -> invariant stall floor.
// R12/R13: VGPR prefetch dead end.  R14: LDS-DMA dbuf + syncthreads = drain0,
//   neutral.  R15: counted-vmcnt pipeline, 68us @ 18% occupancy.
//   SYNTHESIS: MLP varied 6x, occupancy 18-63%, instr 14-108/elem -> read BW
//   pinned at 2.2-2.9 TB/s, warm==cold -> request-path THROUGHPUT ceiling.
//   Last invariant: the 8MB-stride grid-interleaved pattern (every CU walks the
//   whole 84MB; pred/targ congruent mod 2^24 -> same channel/L2-set mapping).
// R16: pattern experiment CRASHED (core dump) -- ambiguous: infra flake
//   (1032s npz push, like R5's flake) or the reg-fence asm x full-unroll combo.
// R17 (this round): SAME experiment, hardened: block-contiguous chunks
//   (block owns 2560 consecutive vec4 = 40KB/array, walked as 1KB wave-lines)
//   + bijective XCD swizzle (each XCD streams one contiguous ~10.5MB region).
//   ALL inline-asm fences removed from the hot path (never helped; only
//   unexonerated crash suspect). Math body = R13 verbatim, per-thread element
//   order unchanged.

#define NBINS  10
#define GRID1  2048
#define BLOCK1 256
#define NXCD   8

typedef float vf4 __attribute__((ext_vector_type(4)));
typedef int   vi4 __attribute__((ext_vector_type(4)));

#if __has_builtin(__builtin_amdgcn_exp2f)
__device__ __forceinline__ float nexp2(float a) { return __builtin_amdgcn_exp2f(a); }
#else
__device__ __forceinline__ float nexp2(float a) { return __expf(a * 0.69314718055994531f); }
#endif
#if __has_builtin(__builtin_amdgcn_logf)
__device__ __forceinline__ float nlog2(float a) { return __builtin_amdgcn_logf(a); }
#else
__device__ __forceinline__ float nlog2(float a) { return __logf(a) * 1.44269504088896341f; }
#endif

#define LOG2E 1.44269504088896341f
#define LN2   0.69314718055994531f

#define VPT   10                    // vec4 per thread on the bench shape
#define CHUNK (VPT * BLOCK1)        // 2560 vec4 per block, contiguous

__global__ __launch_bounds__(BLOCK1) void ghmc_pass1(
    const vf4* __restrict__ pred4,
    const vi4* __restrict__ targ4,
    float* __restrict__ partial_s,   // [NBINS][GRID1] bin-major
    int*   __restrict__ partial_c,   // [NBINS][GRID1] bin-major
    int nvec4)
{
    __shared__ float sred[BLOCK1 / 64][NBINS];
    __shared__ int   cred[BLOCK1 / 64][NBINS];

    float s[NBINS];
#pragma unroll
    for (int b = 0; b < NBINS; ++b) s[b] = 0.0f;
    unsigned long long cnt = 0;   // 10 x 6-bit packed counts; max 40/bin/thread < 63

    const int tid = threadIdx.x;

    // R13's verified phase group (math + per-element order identical; no fences).
    auto group8 = [&](vf4 p0, vi4 t0, vf4 p1, vi4 t1) {
        float x[8], tf[8];
#pragma unroll
        for (int j = 0; j < 4; ++j) {
            x[j]     = p0[j];  tf[j]     = (float)t0[j];
            x[4 + j] = p1[j];  tf[4 + j] = (float)t1[j];
        }
        float z[8];
#pragma unroll
        for (int j = 0; j < 8; ++j)
            z[j] = __builtin_amdgcn_rcpf(1.0f + nexp2(-x[j] * LOG2E));   // sigmoid
        int bi[8]; float bce[8];
#pragma unroll
        for (int j = 0; j < 8; ++j) {
            float g = fabsf(z[j] - tf[j]);                               // [0,1]
            int   b = (int)(g * 10.0f);
            bi[j]   = b > (NBINS - 1) ? (NBINS - 1) : b;
            float sp = nlog2(1.0f + nexp2(z[j] * LOG2E)) * LN2;          // softplus(z)
            bce[j]  = sp - tf[j] * z[j];
        }
#pragma unroll
        for (int j = 0; j < 8; ++j) {
#pragma unroll
            for (int b = 0; b < NBINS; ++b)
                s[b] += (bi[j] == b) ? bce[j] : 0.0f;
            cnt += 1ull << (6 * bi[j]);
        }
    };

    if (nvec4 == GRID1 * CHUNK) {
        // Bijective XCD swizzle (GRID1 % NXCD == 0): HW assigns blockIdx
        // round-robin across XCDs; remap so XCD x owns swizzled ids
        // [x*256, (x+1)*256) -> one contiguous ~10.5MB region per XCD.
        const int swz  = (blockIdx.x % NXCD) * (GRID1 / NXCD) + blockIdx.x / NXCD;
        // Block-contiguous: block 'swz' owns vec4 range [swz*CHUNK, +CHUNK).
        const int base = swz * CHUNK + tid;
#pragma unroll
        for (int k = 0; k < VPT; k += 2) {
            const int i0 = base + k * BLOCK1;
            const int i1 = i0 + BLOCK1;
            vf4 p0 = pred4[i0];
            vi4 t0 = targ4[i0];
            vf4 p1 = pred4[i1];
            vi4 t1 = targ4[i1];
            group8(p0, t0, p1, t1);
        }
    } else {
        // generic fallback: grid-stride (unused on the bench shape)
        const int idx    = blockIdx.x * BLOCK1 + tid;
        const int stride = GRID1 * BLOCK1;
        int i = idx;
        for (; i + stride < nvec4; i += 2 * stride) {
            vf4 p0 = pred4[i];
            vi4 t0 = targ4[i];
            vf4 p1 = pred4[i + stride];
            vi4 t1 = targ4[i + stride];
            group8(p0, t0, p1, t1);
        }
        if (i < nvec4) {
            vf4 p0 = pred4[i];
            vi4 t0 = targ4[i];
#pragma unroll
            for (int j = 0; j < 4; ++j) {
                float tfj = (float)t0[j];
                float zj  = __builtin_amdgcn_rcpf(1.0f + nexp2(-p0[j] * LOG2E));
                float g   = fabsf(zj - tfj);
                int   b   = (int)(g * 10.0f);
                b = b > (NBINS - 1) ? (NBINS - 1) : b;
                float bc  = nlog2(1.0f + nexp2(zj * LOG2E)) * LN2 - tfj * zj;
#pragma unroll
                for (int bb = 0; bb < NBINS; ++bb)
                    s[bb] += (b == bb) ? bc : 0.0f;
                cnt += 1ull << (6 * b);
            }
        }
    }

    // unpack packed counts
    int c[NBINS];
#pragma unroll
    for (int b = 0; b < NBINS; ++b) c[b] = (int)((cnt >> (6 * b)) & 63ull);

    // wave(64) tree reduction
#pragma unroll
    for (int b = 0; b < NBINS; ++b) {
#pragma unroll
        for (int off = 32; off > 0; off >>= 1) {
            s[b] += __shfl_down(s[b], off, 64);
            c[b] += __shfl_down(c[b], off, 64);
        }
    }

    const int wave = tid >> 6;
    if ((tid & 63) == 0) {
#pragma unroll
        for (int b = 0; b < NBINS; ++b) { sred[wave][b] = s[b]; cred[wave][b] = c[b]; }
    }
    __syncthreads();
    if (tid < NBINS) {
        int b = tid;
        partial_s[b * GRID1 + blockIdx.x] = sred[0][b] + sred[1][b] + sred[2][b] + sred[3][b];
        partial_c[b * GRID1 + blockIdx.x] = cred[0][b] + cred[1][b] + cred[2][b] + cred[3][b];
    }
}

#define BLOCK2 1024

__global__ __launch_bounds__(BLOCK2) void ghmc_pass2(
    const float* __restrict__ partial_s,   // [NBINS][GRID1]
    const int*   __restrict__ partial_c,
    float* __restrict__ out,
    int nblocks)
{
    double as[NBINS];
    int    ac[NBINS];
#pragma unroll
    for (int b = 0; b < NBINS; ++b) { as[b] = 0.0; ac[b] = 0; }

    for (int j = threadIdx.x; j < nblocks; j += BLOCK2) {
#pragma unroll
        for (int b = 0; b < NBINS; ++b) {
            as[b] += (double)partial_s[b * nblocks + j];   // coalesced per bin
            ac[b] += partial_c[b * nblocks + j];
        }
    }

#pragma unroll
    for (int b = 0; b < NBINS; ++b) {
#pragma unroll
        for (int off = 32; off > 0; off >>= 1) {
            as[b] += __shfl_down(as[b], off, 64);
            ac[b] += __shfl_down(ac[b], off, 64);
        }
    }

    __shared__ double sds[BLOCK2 / 64][NBINS];
    __shared__ int    sdc[BLOCK2 / 64][NBINS];
    int wave = threadIdx.x >> 6;
    if ((threadIdx.x & 63) == 0) {
#pragma unroll
        for (int b = 0; b < NBINS; ++b) { sds[wave][b] = as[b]; sdc[wave][b] = ac[b]; }
    }
    __syncthreads();

    if (threadIdx.x == 0) {
        int nn = 0;
        double acc = 0.0;
#pragma unroll
        for (int b = 0; b < NBINS; ++b) {
            double sb = 0.0;
            int    cb = 0;
#pragma unroll
            for (int w = 0; w < BLOCK2 / 64; ++w) { sb += sds[w][b]; cb += sdc[w][b]; }
            if (cb > 0) { nn += 1; acc += sb / (double)cb; }
        }
        out[0] = (float)(acc / (double)(nn > 0 ? nn : 1));
    }
}

extern "C" void kernel_launch(void* const* d_in, const int* in_sizes, int n_in,
                              void* d_out, int out_size, void* d_ws, size_t ws_size,
                              hipStream_t stream)
{
    const float* pred = (const float*)d_in[0];
    const int*   targ = (const int*)d_in[1];
    float*       out  = (float*)d_out;

    const int n     = in_sizes[0];   // 20,971,520 (divisible by 4)
    const int nvec4 = n / 4;

    float* partial_s = (float*)d_ws;                                  // NBINS*GRID1 floats
    int*   partial_c = (int*)((char*)d_ws + GRID1 * NBINS * sizeof(float));

    ghmc_pass1<<<GRID1, BLOCK1, 0, stream>>>(
        (const vf4*)pred, (const vi4*)targ, partial_s, partial_c, nvec4);

    ghmc_pass2<<<1, BLOCK2, 0, stream>>>(partial_s, partial_c, out, GRID1);
}